// Round 1
// baseline (1449.640 us; speedup 1.0000x reference)
//
#include <hip/hip_runtime.h>
#include <cstdint>
#include <cstddef>

// Problem: out[M,N] = X[M,K] * W[N,K]^T + bias,  W dequantized from 4-bit.
// M = 4*2048 = 8192, K = 4096, N = 11008.
#define Mdim 8192
#define Ndim 11008
#define Kdim 4096
#define BM 128
#define BN 128
#define BK 64

typedef __attribute__((ext_vector_type(8))) __bf16 bf16x8;   // MFMA A/B operand (4 VGPRs)
typedef __attribute__((ext_vector_type(4))) float floatx4;   // MFMA C/D operand

// round-to-nearest-even fp32 -> bf16 bits
__device__ inline unsigned short f2bf(float f) {
    union { float f; unsigned u; } v; v.f = f;
    unsigned r = v.u + 0x7fffu + ((v.u >> 16) & 1u);
    return (unsigned short)(r >> 16);
}

// ---- pass 1: x fp32 -> bf16 (133 MB read + 67 MB write, HBM-bound) ----
__global__ void cvt_x_kernel(const float4* __restrict__ x, ushort4* __restrict__ o, int n4) {
    int i = blockIdx.x * blockDim.x + threadIdx.x;
    if (i >= n4) return;
    float4 v = x[i];
    ushort4 r;
    r.x = f2bf(v.x); r.y = f2bf(v.y); r.z = f2bf(v.z); r.w = f2bf(v.w);
    o[i] = r;
}

// ---- pass 2: weight int32 -> dequantized bf16 (180 MB read + 90 MB write) ----
__global__ void cvt_w_kernel(const int4* __restrict__ w, ushort4* __restrict__ o,
                             const float* __restrict__ scale, const float* __restrict__ zp,
                             int n4) {
    int i = blockIdx.x * blockDim.x + threadIdx.x;
    if (i >= n4) return;
    float s = scale[0];
    float z = zp[0];
    int4 q = w[i];
    ushort4 r;
    r.x = f2bf(((float)q.x - z) * s);
    r.y = f2bf(((float)q.y - z) * s);
    r.z = f2bf(((float)q.z - z) * s);
    r.w = f2bf(((float)q.w - z) * s);
    o[i] = r;
}

// ---- pass 3: bf16 GEMM, m97-style structure ----
// 128x128 block tile, BK=64 (2 MFMA k-steps / barrier-pair), 256 threads = 4 waves
// in a 2x2 arrangement, each wave owns a 64x64 output tile = 4x4 MFMA 16x16 tiles.
// Staging via global_load_lds width=16 (LDS dest is wave-uniform base + lane*16, so
// LDS is packed row-major [128][64] bf16; bank-conflict fix is an XOR swizzle of the
// 16B chunk column by (row&7), absorbed on the *global* address side of the load).
__global__ __launch_bounds__(256) void gemm_kernel(const short* __restrict__ A,
                                                   const short* __restrict__ B,
                                                   const float* __restrict__ bias,
                                                   float* __restrict__ C) {
    __shared__ __align__(16) short As[BM * BK];
    __shared__ __align__(16) short Bs[BN * BK];

    const int tid  = threadIdx.x;
    const int lane = tid & 63;
    const int wave = tid >> 6;
    const int waveM = wave >> 1;     // 2x2 wave grid
    const int waveN = wave & 1;
    const int l15  = lane & 15;
    const int quad = lane >> 4;

    const int mBase = blockIdx.y * BM;
    const int nBase = blockIdx.x * BN;

    floatx4 acc[4][4];
    #pragma unroll
    for (int i = 0; i < 4; ++i)
        #pragma unroll
        for (int j = 0; j < 4; ++j)
            acc[i][j] = (floatx4)0.0f;

    // Precompute staging addresses. Tile = 128 rows x 8 chunks (16B each) = 1024
    // chunks; 256 threads x 4 rounds. Thread handles linear chunk li; LDS gets
    // chunk li at byte offset li*16 (packed). Global chunk column is XOR-swizzled.
    const short* ga[4];
    const short* gb[4];
    int ldsoff[4];
    #pragma unroll
    for (int r = 0; r < 4; ++r) {
        int li  = r * 256 + tid;     // 0..1023
        int row = li >> 3;           // 0..127
        int pc  = li & 7;            // physical chunk col in LDS
        int gc  = pc ^ (row & 7);    // swizzled global chunk col
        ga[r] = A + (size_t)(mBase + row) * Kdim + gc * 8;
        gb[r] = B + (size_t)(nBase + row) * Kdim + gc * 8;
        ldsoff[r] = li * 8;          // element offset (8 bf16 = 16 B per chunk)
    }

    for (int k0 = 0; k0 < Kdim; k0 += BK) {
        #pragma unroll
        for (int r = 0; r < 4; ++r)
            __builtin_amdgcn_global_load_lds(
                (const __attribute__((address_space(1))) void*)(ga[r] + k0),
                (__attribute__((address_space(3))) void*)(As + ldsoff[r]), 16, 0, 0);
        #pragma unroll
        for (int r = 0; r < 4; ++r)
            __builtin_amdgcn_global_load_lds(
                (const __attribute__((address_space(1))) void*)(gb[r] + k0),
                (__attribute__((address_space(3))) void*)(Bs + ldsoff[r]), 16, 0, 0);
        __syncthreads();   // drains vmcnt for the global_load_lds queue

        #pragma unroll
        for (int kk = 0; kk < 2; ++kk) {          // two k=32 MFMA steps
            bf16x8 af[4], bfr[4];
            const int c = kk * 4 + quad;          // logical chunk col for this lane
            #pragma unroll
            for (int i = 0; i < 4; ++i) {
                // A operand layout: A[m=lane&15][k=quad*8+j]
                int rowA = waveM * 64 + i * 16 + l15;
                af[i]  = *(const bf16x8*)(As + (rowA * 8 + (c ^ (rowA & 7))) * 8);
                // B operand layout: B[k=quad*8+j][n=lane&15]; Bs rows are W rows (= C cols)
                int rowB = waveN * 64 + i * 16 + l15;
                bfr[i] = *(const bf16x8*)(Bs + (rowB * 8 + (c ^ (rowB & 7))) * 8);
            }
            #pragma unroll
            for (int i = 0; i < 4; ++i)
                #pragma unroll
                for (int j = 0; j < 4; ++j)
                    acc[i][j] = __builtin_amdgcn_mfma_f32_16x16x32_bf16(
                        af[i], bfr[j], acc[i][j], 0, 0, 0);
        }
        __syncthreads();   // before next iteration overwrites LDS
    }

    // Epilogue. C/D layout (m89/m91-verified): col = lane&15, row = quad*4 + reg.
    #pragma unroll
    for (int j = 0; j < 4; ++j) {
        int col = nBase + waveN * 64 + j * 16 + l15;
        float bv = bias[col];
        #pragma unroll
        for (int i = 0; i < 4; ++i) {
            int row0 = mBase + waveM * 64 + i * 16 + quad * 4;
            #pragma unroll
            for (int r = 0; r < 4; ++r)
                C[(size_t)(row0 + r) * Ndim + col] = acc[i][j][r] + bv;
        }
    }
}

extern "C" void kernel_launch(void* const* d_in, const int* in_sizes, int n_in,
                              void* d_out, int out_size, void* d_ws, size_t ws_size,
                              hipStream_t stream) {
    const float* x     = (const float*)d_in[0];   // [4,2048,4096] fp32
    const int*   w4    = (const int*)  d_in[1];   // [11008,4096] int32, values 0..15
    const float* scale = (const float*)d_in[2];   // [1]
    const float* zp    = (const float*)d_in[3];   // [1]
    const float* bias  = (const float*)d_in[4];   // [11008]
    float* out = (float*)d_out;                   // [4,2048,11008] fp32

    // Workspace layout: A_bf16 [8192*4096] (67 MB) then W_bf16 [11008*4096] (90 MB).
    short* Abf = (short*)d_ws;
    short* Wbf = Abf + (size_t)Mdim * Kdim;

    const int nx4 = Mdim * Kdim / 4;              // 8388608 -> 32768 blocks
    cvt_x_kernel<<<nx4 / 256, 256, 0, stream>>>((const float4*)x, (ushort4*)Abf, nx4);

    const int nw4 = Ndim * Kdim / 4;              // 11272192 -> 44032 blocks
    cvt_w_kernel<<<nw4 / 256, 256, 0, stream>>>((const int4*)w4, (ushort4*)Wbf, scale, zp, nw4);

    dim3 grid(Ndim / BN, Mdim / BM);              // (86, 64) = 5504 blocks
    gemm_kernel<<<grid, 256, 0, stream>>>(Abf, Wbf, bias, out);
}

// Round 2
// 1284.207 us; speedup vs baseline: 1.1288x; 1.1288x over previous
//
#include <hip/hip_runtime.h>
#include <cstdint>
#include <cstddef>

// Problem: out[M,N] = X[M,K] * W[N,K]^T + bias,  W dequantized from 4-bit.
// M = 4*2048 = 8192, K = 4096, N = 11008.
#define Mdim 8192
#define Ndim 11008
#define Kdim 4096
#define BM 128
#define BN 128
#define BK 64
#define GROUP_M 16   // m-tiles per scheduling group (L3 locality: B fetched <=4x)

typedef __attribute__((ext_vector_type(8))) __bf16 bf16x8;   // MFMA A/B operand (4 VGPRs)
typedef __attribute__((ext_vector_type(4))) float floatx4;   // MFMA C/D operand

// round-to-nearest-even fp32 -> bf16 bits
__device__ inline unsigned f2bf(float f) {
    union { float f; unsigned u; } v; v.f = f;
    unsigned r = v.u + 0x7fffu + ((v.u >> 16) & 1u);
    return r >> 16;
}
__device__ inline unsigned pack2(float lo, float hi) {
    return f2bf(lo) | (f2bf(hi) << 16);
}

// ---- pass 1: x fp32 -> bf16. 8 elems/thread: 2x16B loads, 1x16B store ----
__global__ void cvt_x_kernel(const float4* __restrict__ x, uint4* __restrict__ o, int n8) {
    int i = blockIdx.x * blockDim.x + threadIdx.x;
    if (i >= n8) return;
    float4 a = x[2 * i];
    float4 b = x[2 * i + 1];
    uint4 r;
    r.x = pack2(a.x, a.y);
    r.y = pack2(a.z, a.w);
    r.z = pack2(b.x, b.y);
    r.w = pack2(b.z, b.w);
    o[i] = r;
}

// ---- pass 2: weight int32 -> dequantized bf16. 8 elems/thread ----
__global__ void cvt_w_kernel(const int4* __restrict__ w, uint4* __restrict__ o,
                             const float* __restrict__ scale, const float* __restrict__ zp,
                             int n8) {
    int i = blockIdx.x * blockDim.x + threadIdx.x;
    if (i >= n8) return;
    float s = scale[0];
    float z = zp[0];
    int4 a = w[2 * i];
    int4 b = w[2 * i + 1];
    uint4 r;
    r.x = pack2(((float)a.x - z) * s, ((float)a.y - z) * s);
    r.y = pack2(((float)a.z - z) * s, ((float)a.w - z) * s);
    r.z = pack2(((float)b.x - z) * s, ((float)b.y - z) * s);
    r.w = pack2(((float)b.z - z) * s, ((float)b.w - z) * s);
    o[i] = r;
}

// ---- pass 3: bf16 GEMM, m97-style structure + grouped block scheduling ----
// 128x128 block tile, BK=64, 256 threads = 4 waves (2x2), each wave 4x4 MFMA tiles.
// Staging via global_load_lds width=16; LDS packed row-major [128][64] bf16 with the
// bank-conflict XOR swizzle of the 16B chunk column by (row&7) absorbed on the
// global-address side (R1: SQ_LDS_BANK_CONFLICT == 0).
// Block order: GROUP_M m-tiles iterate together, n advances every GROUP_M blocks ->
// concurrent footprint ~48 B-tiles + 16 A-tiles (~64 MB, L3-resident); B streams
// from HBM at most 64/GROUP_M = 4 times (R1 row-major order fetched B ~32x -> 3 GB).
__global__ __launch_bounds__(256) void gemm_kernel(const short* __restrict__ A,
                                                   const short* __restrict__ B,
                                                   const float* __restrict__ bias,
                                                   float* __restrict__ C) {
    __shared__ __align__(16) short As[BM * BK];
    __shared__ __align__(16) short Bs[BN * BK];

    const int tid  = threadIdx.x;
    const int lane = tid & 63;
    const int wave = tid >> 6;
    const int waveM = wave >> 1;     // 2x2 wave grid
    const int waveN = wave & 1;
    const int l15  = lane & 15;
    const int quad = lane >> 4;

    // Grouped scheduling remap (1D grid, 86*64 blocks).
    const int NT = Ndim / BN;                 // 86 n-tiles
    int pid   = blockIdx.x;
    int group = pid / (GROUP_M * NT);
    int rem   = pid % (GROUP_M * NT);
    int mt    = group * GROUP_M + (rem % GROUP_M);   // m fastest within group
    int nt    = rem / GROUP_M;
    const int mBase = mt * BM;
    const int nBase = nt * BN;

    floatx4 acc[4][4];
    #pragma unroll
    for (int i = 0; i < 4; ++i)
        #pragma unroll
        for (int j = 0; j < 4; ++j)
            acc[i][j] = (floatx4)0.0f;

    // Staging addresses: tile = 128 rows x 8 chunks (16B) = 1024 chunks; 256 thr x 4.
    const short* ga[4];
    const short* gb[4];
    int ldsoff[4];
    #pragma unroll
    for (int r = 0; r < 4; ++r) {
        int li  = r * 256 + tid;     // 0..1023
        int row = li >> 3;           // 0..127
        int pc  = li & 7;            // physical chunk col in LDS
        int gc  = pc ^ (row & 7);    // swizzled global chunk col
        ga[r] = A + (size_t)(mBase + row) * Kdim + gc * 8;
        gb[r] = B + (size_t)(nBase + row) * Kdim + gc * 8;
        ldsoff[r] = li * 8;          // element offset (8 bf16 = 16 B per chunk)
    }

    for (int k0 = 0; k0 < Kdim; k0 += BK) {
        #pragma unroll
        for (int r = 0; r < 4; ++r)
            __builtin_amdgcn_global_load_lds(
                (const __attribute__((address_space(1))) void*)(ga[r] + k0),
                (__attribute__((address_space(3))) void*)(As + ldsoff[r]), 16, 0, 0);
        #pragma unroll
        for (int r = 0; r < 4; ++r)
            __builtin_amdgcn_global_load_lds(
                (const __attribute__((address_space(1))) void*)(gb[r] + k0),
                (__attribute__((address_space(3))) void*)(Bs + ldsoff[r]), 16, 0, 0);
        __syncthreads();   // drains vmcnt for the global_load_lds queue

        #pragma unroll
        for (int kk = 0; kk < 2; ++kk) {          // two k=32 MFMA steps
            bf16x8 af[4], bfr[4];
            const int c = kk * 4 + quad;          // logical chunk col for this lane
            #pragma unroll
            for (int i = 0; i < 4; ++i) {
                // A operand layout: A[m=lane&15][k=quad*8+j]
                int rowA = waveM * 64 + i * 16 + l15;
                af[i]  = *(const bf16x8*)(As + (rowA * 8 + (c ^ (rowA & 7))) * 8);
                // B operand: B[k][n=lane&15]; Bs rows are W rows (= C cols)
                int rowB = waveN * 64 + i * 16 + l15;
                bfr[i] = *(const bf16x8*)(Bs + (rowB * 8 + (c ^ (rowB & 7))) * 8);
            }
            #pragma unroll
            for (int i = 0; i < 4; ++i)
                #pragma unroll
                for (int j = 0; j < 4; ++j)
                    acc[i][j] = __builtin_amdgcn_mfma_f32_16x16x32_bf16(
                        af[i], bfr[j], acc[i][j], 0, 0, 0);
        }
        __syncthreads();   // before next iteration overwrites LDS
    }

    // Epilogue. C/D layout (m89/m91-verified): col = lane&15, row = quad*4 + reg.
    #pragma unroll
    for (int j = 0; j < 4; ++j) {
        int col = nBase + waveN * 64 + j * 16 + l15;
        float bv = bias[col];
        #pragma unroll
        for (int i = 0; i < 4; ++i) {
            int row0 = mBase + waveM * 64 + i * 16 + quad * 4;
            #pragma unroll
            for (int r = 0; r < 4; ++r)
                C[(size_t)(row0 + r) * Ndim + col] = acc[i][j][r] + bv;
        }
    }
}

extern "C" void kernel_launch(void* const* d_in, const int* in_sizes, int n_in,
                              void* d_out, int out_size, void* d_ws, size_t ws_size,
                              hipStream_t stream) {
    const float* x     = (const float*)d_in[0];   // [4,2048,4096] fp32
    const int*   w4    = (const int*)  d_in[1];   // [11008,4096] int32, values 0..15
    const float* scale = (const float*)d_in[2];   // [1]
    const float* zp    = (const float*)d_in[3];   // [1]
    const float* bias  = (const float*)d_in[4];   // [11008]
    float* out = (float*)d_out;                   // [4,2048,11008] fp32

    // Workspace: A_bf16 [8192*4096] (67 MB) then W_bf16 [11008*4096] (90 MB).
    short* Abf = (short*)d_ws;
    short* Wbf = Abf + (size_t)Mdim * Kdim;

    const int nx8 = Mdim * Kdim / 8;              // 4194304 -> 16384 blocks
    cvt_x_kernel<<<nx8 / 256, 256, 0, stream>>>((const float4*)x, (uint4*)Abf, nx8);

    const int nw8 = Ndim * Kdim / 8;              // 5636096 -> 22016 blocks
    cvt_w_kernel<<<nw8 / 256, 256, 0, stream>>>((const int4*)w4, (uint4*)Wbf, scale, zp, nw8);

    const int nblocks = (Ndim / BN) * (Mdim / BM);  // 86*64 = 5504
    gemm_kernel<<<nblocks, 256, 0, stream>>>(Abf, Wbf, bias, out);
}